// Round 6
// baseline (237.575 us; speedup 1.0000x reference)
//
#include <hip/hip_runtime.h>

#define IN_DIM 8192
#define OUT_DIM 8192
#define NROWS 4096
#define THREADS 1024
#define RPB 2                                // rows per block
#define NBLK (NROWS / RPB)                   // 2048 blocks
#define JITERS (OUT_DIM / (THREADS * 4))     // 2

typedef float v4f __attribute__((ext_vector_type(4)));

// GATE_COEF[16][4] from the reference.
__device__ __constant__ float GATE_COEF[16][4] = {
    {0.f, 0.f, 0.f, 0.f}, {0.f, 0.f, 0.f, 1.f}, {0.f, 1.f, 0.f, -1.f}, {0.f, 1.f, 0.f, 0.f},
    {0.f, 0.f, 1.f, -1.f}, {0.f, 0.f, 1.f, 0.f}, {0.f, 1.f, 1.f, -2.f}, {0.f, 1.f, 1.f, -1.f},
    {1.f, -1.f, -1.f, 1.f}, {1.f, -1.f, -1.f, 2.f}, {1.f, 0.f, -1.f, 0.f}, {1.f, 0.f, -1.f, 1.f},
    {1.f, -1.f, 0.f, 0.f}, {1.f, -1.f, 0.f, 1.f}, {1.f, 0.f, 0.f, -1.f}, {1.f, 0.f, 0.f, 0.f}};

// Kernel A: c[j] = softmax(weights[j,:]) @ GATE_COEF, stored SoA planes.
__global__ __launch_bounds__(256) void compute_c_kernel(const float* __restrict__ w,
                                                        float* __restrict__ cp) {
    int j = blockIdx.x * blockDim.x + threadIdx.x;
    if (j >= OUT_DIM) return;
    const float4* wv = (const float4*)(w + (size_t)j * 16);
    float4 w0 = wv[0], w1 = wv[1], w2 = wv[2], w3 = wv[3];
    float wa[16] = {w0.x, w0.y, w0.z, w0.w, w1.x, w1.y, w1.z, w1.w,
                    w2.x, w2.y, w2.z, w2.w, w3.x, w3.y, w3.z, w3.w};
    float m = wa[0];
#pragma unroll
    for (int k = 1; k < 16; ++k) m = fmaxf(m, wa[k]);
    float p[16];
    float s = 0.f;
#pragma unroll
    for (int k = 0; k < 16; ++k) {
        p[k] = __expf(wa[k] - m);
        s += p[k];
    }
    float inv = 1.f / s;
    float c0 = 0.f, c1 = 0.f, c2 = 0.f, c3 = 0.f;
#pragma unroll
    for (int k = 0; k < 16; ++k) {
        c0 = fmaf(p[k], GATE_COEF[k][0], c0);
        c1 = fmaf(p[k], GATE_COEF[k][1], c1);
        c2 = fmaf(p[k], GATE_COEF[k][2], c2);
        c3 = fmaf(p[k], GATE_COEF[k][3], c3);
    }
    cp[j] = c0 * inv;
    cp[j + OUT_DIM] = c1 * inv;
    cp[j + 2 * OUT_DIM] = c2 * inv;
    cp[j + 3 * OUT_DIM] = c3 * inv;
}

// Kernel B: R0's winning structure (2 rows/block, 2048 blocks, 4 generations
// of 2 resident blocks/CU) with two changes:
//  1. 1024-thread blocks: LDS still allows 2 blocks/CU, so 32 waves/CU
//     (8/SIMD) -- double the latency-hiding of the 512-thread version.
//     R4 counters showed the latency-bound signature (hbm 3.7 TB/s, VALUBusy
//     4.4%, occ 38%): more waves is the canonical fix.
//  2. global_load_lds staging (verified m97 pattern: glds + __syncthreads):
//     no VGPR round-trip, stage = 4 fire-and-forget DMA issues/thread with
//     idx+c iter-0 prefetches under the drain.
__global__ __launch_bounds__(THREADS, 8) void gate_kernel(const float* __restrict__ x,
                                                          const float* __restrict__ cp,
                                                          const int* __restrict__ idx0,
                                                          const int* __restrict__ idx1,
                                                          float* __restrict__ out) {
    __shared__ __align__(16) float rows[RPB * IN_DIM];  // 64 KB
    const int r0 = blockIdx.x * RPB;
    const int tid = threadIdx.x;

    // Stage both rows straight into LDS (linear dest = lane*16, required by HW).
    {
        const float* xr = x + (size_t)r0 * IN_DIM;
#pragma unroll
        for (int t = 0; t < 2 * RPB; ++t) {
            const int off = tid * 4 + t * (THREADS * 4);  // covers 2*IN_DIM floats
            __builtin_amdgcn_global_load_lds(
                (const __attribute__((address_space(1))) void*)(xr + off),
                (__attribute__((address_space(3))) void*)(rows + off), 16, 0, 0);
        }
    }

    const float* __restrict__ c0p = cp;
    const float* __restrict__ c1p = cp + OUT_DIM;
    const float* __restrict__ c2p = cp + 2 * OUT_DIM;
    const float* __restrict__ c3p = cp + 3 * OUT_DIM;

    // Prefetch iteration-0 idx + c under the staging drain.
    const int j0 = tid * 4;
    int4 pi0 = *(const int4*)(idx0 + j0);
    int4 pi1 = *(const int4*)(idx1 + j0);
    v4f pc0 = *(const v4f*)(c0p + j0);
    v4f pc1 = *(const v4f*)(c1p + j0);
    v4f pc2 = *(const v4f*)(c2p + j0);
    v4f pc3 = *(const v4f*)(c3p + j0);

    __syncthreads();  // drains glds (vmcnt) + barrier: LDS rows valid

    float* o0 = out + (size_t)r0 * OUT_DIM;
    float* o1 = out + (size_t)(r0 + 1) * OUT_DIM;

#pragma unroll
    for (int k = 0; k < JITERS; ++k) {
        const int j = k * (THREADS * 4) + tid * 4;
        const int4 i0 = pi0;
        const int4 i1 = pi1;
        const v4f c0v = pc0, c1v = pc1, c2v = pc2, c3v = pc3;
        if (k < JITERS - 1) {
            const int jn = j + THREADS * 4;
            pi0 = *(const int4*)(idx0 + jn);
            pi1 = *(const int4*)(idx1 + jn);
            pc0 = *(const v4f*)(c0p + jn);
            pc1 = *(const v4f*)(c1p + jn);
            pc2 = *(const v4f*)(c2p + jn);
            pc3 = *(const v4f*)(c3p + jn);
        }
        // Gathers for both rows issued together (16 independent ds_reads).
        v4f a0, b0, a1, b1;
        a0.x = rows[i0.x]; a0.y = rows[i0.y]; a0.z = rows[i0.z]; a0.w = rows[i0.w];
        b0.x = rows[i1.x]; b0.y = rows[i1.y]; b0.z = rows[i1.z]; b0.w = rows[i1.w];
        a1.x = rows[IN_DIM + i0.x]; a1.y = rows[IN_DIM + i0.y];
        a1.z = rows[IN_DIM + i0.z]; a1.w = rows[IN_DIM + i0.w];
        b1.x = rows[IN_DIM + i1.x]; b1.y = rows[IN_DIM + i1.y];
        b1.z = rows[IN_DIM + i1.z]; b1.w = rows[IN_DIM + i1.w];

        const v4f r0v = c0v + c1v * a0 + c2v * b0 + c3v * (a0 * b0);
        const v4f r1v = c0v + c1v * a1 + c2v * b1 + c3v * (a1 * b1);
        *(v4f*)(o0 + j) = r0v;
        *(v4f*)(o1 + j) = r1v;
    }
}

extern "C" void kernel_launch(void* const* d_in, const int* in_sizes, int n_in,
                              void* d_out, int out_size, void* d_ws, size_t ws_size,
                              hipStream_t stream) {
    const float* x = (const float*)d_in[0];
    const float* weights = (const float*)d_in[1];
    const int* idx0 = (const int*)d_in[2];
    const int* idx1 = (const int*)d_in[3];
    float* out = (float*)d_out;
    float* cp = (float*)d_ws;  // 4 planes x OUT_DIM floats = 128 KB scratch

    compute_c_kernel<<<OUT_DIM / 256, 256, 0, stream>>>(weights, cp);
    gate_kernel<<<NBLK, THREADS, 0, stream>>>(x, cp, idx0, idx1, out);
}